// Round 1
// baseline (900.608 us; speedup 1.0000x reference)
//
#include <hip/hip_runtime.h>
#include <hip/hip_bf16.h>

// GraphGATNet: 2-layer GAT, N=50000 nodes, E=800000 edges (+N self-loops)
// Layer1: 128 -> 8 heads x 16, concat, relu. Layer2: 128 -> 1 head x 128.
// Softmax over incoming edges per destination node.
// Trick: skip segment-max (mathematically identity for softmax ratio),
// accumulate unnormalized w*h[src] and w per dst in ONE edge pass (atomics),
// normalize per node afterwards.

constexpr int N_NODES = 50000;
constexpr int E_EDGES = 800000;
constexpr int C = 128;            // channels in/out of both layers
constexpr float NEG_SLOPE = 0.2f;
constexpr float EPS = 1e-16f;

__device__ __forceinline__ float lrelu(float x) { return x > 0.f ? x : NEG_SLOPE * x; }

// Computes H = X @ W (rows n0..n0+7), per-node attention dots, and zeroes the
// edge-pass accumulators for those rows.
template <int HEADS_T, int HID_T>
__global__ __launch_bounds__(128) void gemm_att_kernel(
    const float* __restrict__ X, const float* __restrict__ W,
    const float* __restrict__ attS, const float* __restrict__ attD,
    float* __restrict__ H, float* __restrict__ aS, float* __restrict__ aD,
    float* __restrict__ outAcc, float* __restrict__ denom)
{
    __shared__ float xs[8][C];
    __shared__ float hs[8][C];
    const int c = threadIdx.x;          // 0..127
    const int n0 = blockIdx.x * 8;

    #pragma unroll
    for (int r = 0; r < 8; ++r) xs[r][c] = X[(n0 + r) * C + c];
    __syncthreads();

    float acc[8];
    #pragma unroll
    for (int r = 0; r < 8; ++r) acc[r] = 0.f;

    for (int k = 0; k < C; ++k) {
        const float wv = W[k * C + c];
        #pragma unroll
        for (int r = 0; r < 8; ++r) acc[r] += xs[r][k] * wv;
    }

    #pragma unroll
    for (int r = 0; r < 8; ++r) {
        hs[r][c] = acc[r];
        H[(n0 + r) * C + c] = acc[r];
        outAcc[(n0 + r) * C + c] = 0.f;   // zero accumulator (safe: xs already loaded)
    }
    __syncthreads();

    // attention dots: thread t handles (row = t / HEADS_T, head = t % HEADS_T)
    if (c < HEADS_T * 8) {
        const int h = c % HEADS_T, r = c / HEADS_T;
        float sv = 0.f, dv = 0.f;
        #pragma unroll 4
        for (int j = 0; j < HID_T; ++j) {
            const float hv = hs[r][h * HID_T + j];
            sv += hv * attS[h * HID_T + j];
            dv += hv * attD[h * HID_T + j];
        }
        aS[(n0 + r) * HEADS_T + h] = sv;
        aD[(n0 + r) * HEADS_T + h] = dv;
        denom[(n0 + r) * HEADS_T + h] = 0.f;
    }
}

// Layer 1 edge pass: 8 heads x 16 hid. One wave (64 lanes) per edge; lane l
// handles channels l and l+64 (heads l>>4 and (l>>4)+4).
__global__ __launch_bounds__(256) void edge_l1_kernel(
    const int* __restrict__ ei,
    const float* __restrict__ aS, const float* __restrict__ aD,
    const float* __restrict__ H,
    float* __restrict__ outAcc, float* __restrict__ denom)
{
    const int Etot = E_EDGES + N_NODES;
    const int gw = (blockIdx.x * blockDim.x + threadIdx.x) >> 6;
    const int lane = threadIdx.x & 63;
    const int nw = (gridDim.x * blockDim.x) >> 6;

    for (int e = gw; e < Etot; e += nw) {
        int s, d;
        if (e < E_EDGES) { s = ei[e]; d = ei[E_EDGES + e]; }
        else             { s = d = e - E_EDGES; }

        const int h0 = lane >> 4;
        const float w0 = __expf(lrelu(aS[s * 8 + h0]     + aD[d * 8 + h0]));
        const float w1 = __expf(lrelu(aS[s * 8 + h0 + 4] + aD[d * 8 + h0 + 4]));

        atomicAdd(&outAcc[d * C + lane],      w0 * H[s * C + lane]);
        atomicAdd(&outAcc[d * C + lane + 64], w1 * H[s * C + lane + 64]);
        if (lane < 8) {
            const float wd = __expf(lrelu(aS[s * 8 + lane] + aD[d * 8 + lane]));
            atomicAdd(&denom[d * 8 + lane], wd);
        }
    }
}

// Layer 2 edge pass: 1 head x 128.
__global__ __launch_bounds__(256) void edge_l2_kernel(
    const int* __restrict__ ei,
    const float* __restrict__ aS, const float* __restrict__ aD,
    const float* __restrict__ H,
    float* __restrict__ outAcc, float* __restrict__ denom)
{
    const int Etot = E_EDGES + N_NODES;
    const int gw = (blockIdx.x * blockDim.x + threadIdx.x) >> 6;
    const int lane = threadIdx.x & 63;
    const int nw = (gridDim.x * blockDim.x) >> 6;

    for (int e = gw; e < Etot; e += nw) {
        int s, d;
        if (e < E_EDGES) { s = ei[e]; d = ei[E_EDGES + e]; }
        else             { s = d = e - E_EDGES; }

        const float w = __expf(lrelu(aS[s] + aD[d]));
        atomicAdd(&outAcc[d * C + lane],      w * H[s * C + lane]);
        atomicAdd(&outAcc[d * C + lane + 64], w * H[s * C + lane + 64]);
        if (lane == 0) atomicAdd(&denom[d], w);
    }
}

// out1 = relu(acc / (denom+eps) + b1), in place OK (elementwise).
__global__ __launch_bounds__(256) void norm_relu_kernel(
    const float* __restrict__ outAcc, const float* __restrict__ denom,
    const float* __restrict__ bias, float* __restrict__ out)
{
    const int i = blockIdx.x * blockDim.x + threadIdx.x;
    if (i >= N_NODES * C) return;
    const int n = i >> 7, c = i & 127;
    const float v = outAcc[i] / (denom[n * 8 + (c >> 4)] + EPS) + bias[c];
    out[i] = fmaxf(v, 0.f);
}

__global__ __launch_bounds__(256) void norm_final_kernel(
    const float* __restrict__ outAcc, const float* __restrict__ denom,
    const float* __restrict__ bias, float* __restrict__ out)
{
    const int i = blockIdx.x * blockDim.x + threadIdx.x;
    if (i >= N_NODES * C) return;
    const int n = i >> 7, c = i & 127;
    out[i] = outAcc[i] / (denom[n] + EPS) + bias[c];
}

extern "C" void kernel_launch(void* const* d_in, const int* in_sizes, int n_in,
                              void* d_out, int out_size, void* d_ws, size_t ws_size,
                              hipStream_t stream) {
    const float* x        = (const float*)d_in[0];
    const int*   ei       = (const int*)  d_in[1];
    const float* W1       = (const float*)d_in[2];
    const float* att_src1 = (const float*)d_in[3];
    const float* att_dst1 = (const float*)d_in[4];
    const float* b1       = (const float*)d_in[5];
    const float* W2       = (const float*)d_in[6];
    const float* att_src2 = (const float*)d_in[7];
    const float* att_dst2 = (const float*)d_in[8];
    const float* b2       = (const float*)d_in[9];
    float* out = (float*)d_out;

    // Workspace layout (floats)
    float* bufA  = (float*)d_ws;                 // N*C  : h1, then h2
    float* bufB  = bufA + (size_t)N_NODES * C;   // N*C  : acc1 -> out1 -> acc2
    float* aS    = bufB + (size_t)N_NODES * C;   // N*8
    float* aD    = aS   + (size_t)N_NODES * 8;   // N*8
    float* denom = aD   + (size_t)N_NODES * 8;   // N*8

    const int gemm_blocks = N_NODES / 8;         // 6250
    const int norm_blocks = (N_NODES * C) / 256; // 25000
    const int edge_blocks = 8192;

    // ---- Layer 1 ----
    gemm_att_kernel<8, 16><<<gemm_blocks, 128, 0, stream>>>(
        x, W1, att_src1, att_dst1, bufA, aS, aD, bufB, denom);
    edge_l1_kernel<<<edge_blocks, 256, 0, stream>>>(ei, aS, aD, bufA, bufB, denom);
    norm_relu_kernel<<<norm_blocks, 256, 0, stream>>>(bufB, denom, b1, bufB);

    // ---- Layer 2 ---- (reads bufB rows into LDS before zeroing them as acc)
    gemm_att_kernel<1, 128><<<gemm_blocks, 128, 0, stream>>>(
        bufB, W2, att_src2, att_dst2, bufA, aS, aD, bufB, denom);
    edge_l2_kernel<<<edge_blocks, 256, 0, stream>>>(ei, aS, aD, bufA, bufB, denom);
    norm_final_kernel<<<norm_blocks, 256, 0, stream>>>(bufB, denom, b2, out);
}

// Round 2
// 370.965 us; speedup vs baseline: 2.4277x; 2.4277x over previous
//
#include <hip/hip_runtime.h>
#include <hip/hip_bf16.h>

// GraphGATNet: 2-layer GAT. Round 2: replace atomic edge-scatter (462MB of
// device-scope fp32 atomic writes per layer, 400us each) with a dst-CSR built
// per call (counting sort) + one-block-per-dst gather aggregation with fused
// softmax-normalize/bias/relu. Softmax max-subtraction skipped (identity).

constexpr int N_NODES = 50000;
constexpr int E_EDGES = 800000;
constexpr int ETOT = E_EDGES + N_NODES;   // + self loops
constexpr int C = 128;
constexpr float NEG_SLOPE = 0.2f;
constexpr float EPS = 1e-16f;

constexpr int SCAN_BLK = 512;
constexpr int NBLK_SCAN = (N_NODES + SCAN_BLK - 1) / SCAN_BLK;  // 98

__device__ __forceinline__ float lrelu(float x) { return x > 0.f ? x : NEG_SLOPE * x; }

// ---------------- CSR build (counting sort by dst) ----------------
__global__ __launch_bounds__(256) void zero_counts(int* cnt, int* cursor) {
    int i = blockIdx.x * blockDim.x + threadIdx.x;
    if (i < N_NODES) { cnt[i] = 0; cursor[i] = 0; }
}

__global__ __launch_bounds__(256) void count_kernel(const int* __restrict__ ei,
                                                    int* __restrict__ cnt) {
    int e = blockIdx.x * blockDim.x + threadIdx.x;
    if (e >= ETOT) return;
    int d = (e < E_EDGES) ? ei[E_EDGES + e] : (e - E_EDGES);
    atomicAdd(&cnt[d], 1);
}

__global__ __launch_bounds__(SCAN_BLK) void block_sums(const int* __restrict__ cnt,
                                                       int* __restrict__ bsum) {
    __shared__ int sm[SCAN_BLK];
    int i = blockIdx.x * SCAN_BLK + threadIdx.x;
    sm[threadIdx.x] = (i < N_NODES) ? cnt[i] : 0;
    __syncthreads();
    for (int off = SCAN_BLK / 2; off > 0; off >>= 1) {
        if (threadIdx.x < off) sm[threadIdx.x] += sm[threadIdx.x + off];
        __syncthreads();
    }
    if (threadIdx.x == 0) bsum[blockIdx.x] = sm[0];
}

__global__ void scan_bsums(int* bsum) {   // exclusive scan of 98 values
    if (threadIdx.x == 0 && blockIdx.x == 0) {
        int acc = 0;
        for (int i = 0; i < NBLK_SCAN; ++i) { int v = bsum[i]; bsum[i] = acc; acc += v; }
    }
}

__global__ __launch_bounds__(SCAN_BLK) void scan_final(const int* __restrict__ cnt,
                                                       const int* __restrict__ bsum,
                                                       int* __restrict__ rowptr) {
    __shared__ int sm[SCAN_BLK];
    int i = blockIdx.x * SCAN_BLK + threadIdx.x;
    int v = (i < N_NODES) ? cnt[i] : 0;
    sm[threadIdx.x] = v;
    __syncthreads();
    for (int off = 1; off < SCAN_BLK; off <<= 1) {   // inclusive Hillis-Steele
        int t = (threadIdx.x >= off) ? sm[threadIdx.x - off] : 0;
        __syncthreads();
        sm[threadIdx.x] += t;
        __syncthreads();
    }
    if (i < N_NODES) rowptr[i] = bsum[blockIdx.x] + sm[threadIdx.x] - v;
    if (blockIdx.x == 0 && threadIdx.x == 0) rowptr[N_NODES] = ETOT;
}

__global__ __launch_bounds__(256) void scatter_kernel(const int* __restrict__ ei,
                                                      const int* __restrict__ rowptr,
                                                      int* __restrict__ cursor,
                                                      int* __restrict__ csrc) {
    int e = blockIdx.x * blockDim.x + threadIdx.x;
    if (e >= ETOT) return;
    int s, d;
    if (e < E_EDGES) { s = ei[e]; d = ei[E_EDGES + e]; }
    else             { s = d = e - E_EDGES; }
    int pos = rowptr[d] + atomicAdd(&cursor[d], 1);
    csrc[pos] = s;
}

// ---------------- dense: H = X @ W + attention dots ----------------
template <int HEADS_T, int HID_T>
__global__ __launch_bounds__(128) void gemm_att_kernel(
    const float* __restrict__ X, const float* __restrict__ W,
    const float* __restrict__ attS, const float* __restrict__ attD,
    float* __restrict__ H, float* __restrict__ aS, float* __restrict__ aD)
{
    __shared__ float xs[8][C];
    __shared__ float hs[8][C];
    const int c = threadIdx.x;          // 0..127
    const int n0 = blockIdx.x * 8;

    #pragma unroll
    for (int r = 0; r < 8; ++r) xs[r][c] = X[(n0 + r) * C + c];
    __syncthreads();

    float acc[8];
    #pragma unroll
    for (int r = 0; r < 8; ++r) acc[r] = 0.f;

    for (int k = 0; k < C; ++k) {
        const float wv = W[k * C + c];
        #pragma unroll
        for (int r = 0; r < 8; ++r) acc[r] += xs[r][k] * wv;
    }

    #pragma unroll
    for (int r = 0; r < 8; ++r) {
        hs[r][c] = acc[r];
        H[(n0 + r) * C + c] = acc[r];
    }
    __syncthreads();

    if (c < HEADS_T * 8) {
        const int h = c % HEADS_T, r = c / HEADS_T;
        float sv = 0.f, dv = 0.f;
        #pragma unroll 4
        for (int j = 0; j < HID_T; ++j) {
            const float hv = hs[r][h * HID_T + j];
            sv += hv * attS[h * HID_T + j];
            dv += hv * attD[h * HID_T + j];
        }
        aS[(n0 + r) * HEADS_T + h] = sv;
        aD[(n0 + r) * HEADS_T + h] = dv;
    }
}

// ---------------- CSR aggregation, fused normalize/bias/(relu) ----------------
template <int HEADS_T, bool RELU>
__global__ __launch_bounds__(128) void agg_kernel(
    const int* __restrict__ rowptr, const int* __restrict__ csrc,
    const float* __restrict__ aS, const float* __restrict__ aD,
    const float* __restrict__ Hm, const float* __restrict__ bias,
    float* __restrict__ out)
{
    const int d = blockIdx.x;
    const int c = threadIdx.x;           // channel
    const int h = (HEADS_T == 8) ? (c >> 4) : 0;
    const float ad = aD[d * HEADS_T + h];

    int i = rowptr[d];
    const int end = rowptr[d + 1];
    float acc = 0.f, ws = 0.f;
    int s = (i < end) ? csrc[i] : 0;     // prefetch
    while (i < end) {
        const int scur = s;
        ++i;
        if (i < end) s = csrc[i];
        const float w = __expf(lrelu(aS[scur * HEADS_T + h] + ad));
        acc += w * Hm[scur * C + c];
        ws  += w;
    }
    float v = acc / (ws + EPS) + bias[c];
    out[d * C + c] = RELU ? fmaxf(v, 0.f) : v;
}

extern "C" void kernel_launch(void* const* d_in, const int* in_sizes, int n_in,
                              void* d_out, int out_size, void* d_ws, size_t ws_size,
                              hipStream_t stream) {
    const float* x        = (const float*)d_in[0];
    const int*   ei       = (const int*)  d_in[1];
    const float* W1       = (const float*)d_in[2];
    const float* att_src1 = (const float*)d_in[3];
    const float* att_dst1 = (const float*)d_in[4];
    const float* b1       = (const float*)d_in[5];
    const float* W2       = (const float*)d_in[6];
    const float* att_src2 = (const float*)d_in[7];
    const float* att_dst2 = (const float*)d_in[8];
    const float* b2       = (const float*)d_in[9];
    float* out = (float*)d_out;

    // Workspace layout
    float* hbuf = (float*)d_ws;                    // N*C : h1, then h2
    float* o1   = hbuf + (size_t)N_NODES * C;      // N*C : relu(out1)
    float* aS1  = o1   + (size_t)N_NODES * C;      // N*8
    float* aD1  = aS1  + (size_t)N_NODES * 8;      // N*8
    float* aS2  = aD1  + (size_t)N_NODES * 8;      // N
    float* aD2  = aS2  + (size_t)N_NODES;          // N
    int* cnt    = (int*)(aD2 + N_NODES);           // N
    int* cursor = cnt    + N_NODES;                // N
    int* rowptr = cursor + N_NODES;                // N+1
    int* bsum   = rowptr + N_NODES + 1;            // NBLK_SCAN
    int* csrc   = bsum   + NBLK_SCAN + 1;          // ETOT

    const int nblk  = (N_NODES + 255) / 256;
    const int eblk  = (ETOT + 255) / 256;
    const int gemm_blocks = N_NODES / 8;           // 6250

    // CSR build (graph is identical for both layers)
    zero_counts<<<nblk, 256, 0, stream>>>(cnt, cursor);
    count_kernel<<<eblk, 256, 0, stream>>>(ei, cnt);
    block_sums<<<NBLK_SCAN, SCAN_BLK, 0, stream>>>(cnt, bsum);
    scan_bsums<<<1, 64, 0, stream>>>(bsum);
    scan_final<<<NBLK_SCAN, SCAN_BLK, 0, stream>>>(cnt, bsum, rowptr);
    scatter_kernel<<<eblk, 256, 0, stream>>>(ei, rowptr, cursor, csrc);

    // Layer 1
    gemm_att_kernel<8, 16><<<gemm_blocks, 128, 0, stream>>>(
        x, W1, att_src1, att_dst1, hbuf, aS1, aD1);
    agg_kernel<8, true><<<N_NODES, 128, 0, stream>>>(
        rowptr, csrc, aS1, aD1, hbuf, b1, o1);

    // Layer 2 (hbuf reused for h2)
    gemm_att_kernel<1, 128><<<gemm_blocks, 128, 0, stream>>>(
        o1, W2, att_src2, att_dst2, hbuf, aS2, aD2);
    agg_kernel<1, false><<<N_NODES, 128, 0, stream>>>(
        rowptr, csrc, aS2, aD2, hbuf, b2, out);
}

// Round 3
// 266.013 us; speedup vs baseline: 3.3856x; 1.3945x over previous
//
#include <hip/hip_runtime.h>

// GraphGATNet 2-layer GAT. Round 3:
//  - H stored bf16 -> halves the dominant random row-gather in agg (was 230MB FETCH @106us)
//  - agg: one wave per dst node, ushort2 payload, shfl-broadcast weights (1 exp per edge-head)
//  - GEMM via mfma_f32_16x16x32_bf16 (x converted to bf16 during LDS staging, W pre-transposed
//    to bf16; XOR-swizzled LDS to avoid stride-256B bank conflicts)
//  - attention dots in a small separate kernel reading bf16 H
//  - CSR build as before, single-thread 98-scan replaced by one-block LDS scan

constexpr int N_NODES = 50000;
constexpr int E_EDGES = 800000;
constexpr int ETOT = E_EDGES + N_NODES;
constexpr float NEG_SLOPE = 0.2f;
constexpr float EPS = 1e-16f;
constexpr int SCAN_BLK = 512;
constexpr int NBLK_SCAN = (N_NODES + SCAN_BLK - 1) / SCAN_BLK;   // 98

typedef short bf16x8 __attribute__((ext_vector_type(8)));
typedef float f32x4 __attribute__((ext_vector_type(4)));

__device__ __forceinline__ float lrelu(float x) { return x > 0.f ? x : NEG_SLOPE * x; }
__device__ __forceinline__ ushort f2bf(float f) {
    uint u = __float_as_uint(f);
    return (ushort)((u + 0x7fffu + ((u >> 16) & 1u)) >> 16);
}
__device__ __forceinline__ float bf2f(uint u) { return __uint_as_float(u << 16); }

// ---------------- CSR build ----------------
__global__ __launch_bounds__(256) void zero_counts(int* cnt, int* cursor) {
    int i = blockIdx.x * blockDim.x + threadIdx.x;
    if (i < N_NODES) { cnt[i] = 0; cursor[i] = 0; }
}

__global__ __launch_bounds__(256) void count_kernel(const int* __restrict__ ei,
                                                    int* __restrict__ cnt) {
    int e = blockIdx.x * blockDim.x + threadIdx.x;
    if (e >= ETOT) return;
    int d = (e < E_EDGES) ? ei[E_EDGES + e] : (e - E_EDGES);
    atomicAdd(&cnt[d], 1);
}

__global__ __launch_bounds__(SCAN_BLK) void block_sums(const int* __restrict__ cnt,
                                                       int* __restrict__ bsum) {
    __shared__ int sm[SCAN_BLK];
    int i = blockIdx.x * SCAN_BLK + threadIdx.x;
    sm[threadIdx.x] = (i < N_NODES) ? cnt[i] : 0;
    __syncthreads();
    for (int off = SCAN_BLK / 2; off > 0; off >>= 1) {
        if (threadIdx.x < off) sm[threadIdx.x] += sm[threadIdx.x + off];
        __syncthreads();
    }
    if (threadIdx.x == 0) bsum[blockIdx.x] = sm[0];
}

__global__ __launch_bounds__(128) void scan98(int* bsum) {   // exclusive scan, 98 vals
    __shared__ int sm[128];
    int t = threadIdx.x;
    int v = (t < NBLK_SCAN) ? bsum[t] : 0;
    sm[t] = v;
    __syncthreads();
    for (int off = 1; off < 128; off <<= 1) {
        int x = (t >= off) ? sm[t - off] : 0;
        __syncthreads();
        sm[t] += x;
        __syncthreads();
    }
    if (t < NBLK_SCAN) bsum[t] = sm[t] - v;
}

__global__ __launch_bounds__(SCAN_BLK) void scan_final(const int* __restrict__ cnt,
                                                       const int* __restrict__ bsum,
                                                       int* __restrict__ rowptr) {
    __shared__ int sm[SCAN_BLK];
    int i = blockIdx.x * SCAN_BLK + threadIdx.x;
    int v = (i < N_NODES) ? cnt[i] : 0;
    sm[threadIdx.x] = v;
    __syncthreads();
    for (int off = 1; off < SCAN_BLK; off <<= 1) {
        int t = (threadIdx.x >= off) ? sm[threadIdx.x - off] : 0;
        __syncthreads();
        sm[threadIdx.x] += t;
        __syncthreads();
    }
    if (i < N_NODES) rowptr[i] = bsum[blockIdx.x] + sm[threadIdx.x] - v;
    if (blockIdx.x == 0 && threadIdx.x == 0) rowptr[N_NODES] = ETOT;
}

__global__ __launch_bounds__(256) void scatter_kernel(const int* __restrict__ ei,
                                                      const int* __restrict__ rowptr,
                                                      int* __restrict__ cursor,
                                                      int* __restrict__ csrc) {
    int e = blockIdx.x * blockDim.x + threadIdx.x;
    if (e >= ETOT) return;
    int s, d;
    if (e < E_EDGES) { s = ei[e]; d = ei[E_EDGES + e]; }
    else             { s = d = e - E_EDGES; }
    int pos = rowptr[d] + atomicAdd(&cursor[d], 1);
    csrc[pos] = s;
}

// ---------------- W -> bf16 transposed ----------------
// blockIdx 0: W1, 1: W2. Output Wt[n][k] = W[k][n] as bf16.
__global__ __launch_bounds__(256) void convert_W(const float* __restrict__ W1,
                                                 const float* __restrict__ W2,
                                                 ushort* __restrict__ W1t,
                                                 ushort* __restrict__ W2t) {
    const float* W = (blockIdx.x == 0) ? W1 : W2;
    ushort* Wt = (blockIdx.x == 0) ? W1t : W2t;
    const int t = threadIdx.x;
    const int n = t >> 1, k0 = (t & 1) * 64;
    for (int k = 0; k < 64; k += 2) {
        uint lo = f2bf(W[(size_t)(k0 + k) * 128 + n]);
        uint hi = f2bf(W[(size_t)(k0 + k + 1) * 128 + n]);
        *(uint*)&Wt[(size_t)n * 128 + k0 + k] = lo | (hi << 16);
    }
}

// ---------------- MFMA GEMM: H(bf16) = X(fp32) @ W, tile 64x128x128 ----------------
// LDS layout (both X and W): [row][chunk] where chunk = 16B (8 bf16) unit,
// physical chunk = cx ^ (row & 7)  (XOR swizzle to break stride-256B conflicts).
__global__ __launch_bounds__(256) void mfma_gemm(const float* __restrict__ X,
                                                 const ushort* __restrict__ Wt,
                                                 ushort* __restrict__ H,
                                                 int nrows) {
    __shared__ ushort lx[64 * 128];    // 16 KB
    __shared__ ushort lw[128 * 128];   // 32 KB
    const int t = threadIdx.x;
    const int r0 = blockIdx.x * 64;

    // stage W: thread t -> row n = t>>1, chunks 8*(t&1)..+7 (coalesced 16B loads)
    {
        const int n = t >> 1, half = t & 1;
        const ushort* src = Wt + (size_t)n * 128 + half * 64;
        #pragma unroll
        for (int c = 0; c < 8; ++c) {
            int cx = half * 8 + c;
            uint4 v = *(const uint4*)(src + c * 8);
            *(uint4*)&lw[(n * 16 + (cx ^ (n & 7))) * 8] = v;
        }
    }
    // stage X: thread t -> local row r = t>>2, quarter q = t&3 (32 floats), convert to bf16
    {
        const int r = t >> 2, q = t & 3;
        const int grow = r0 + r;
        uint4 z = {0, 0, 0, 0};
        #pragma unroll
        for (int cc = 0; cc < 4; ++cc) {
            int cx = q * 4 + cc;
            uint4 packed = z;
            if (grow < nrows) {
                const float4 f0 = *(const float4*)(X + (size_t)grow * 128 + cx * 8);
                const float4 f1 = *(const float4*)(X + (size_t)grow * 128 + cx * 8 + 4);
                packed.x = (uint)f2bf(f0.x) | ((uint)f2bf(f0.y) << 16);
                packed.y = (uint)f2bf(f0.z) | ((uint)f2bf(f0.w) << 16);
                packed.z = (uint)f2bf(f1.x) | ((uint)f2bf(f1.y) << 16);
                packed.w = (uint)f2bf(f1.z) | ((uint)f2bf(f1.w) << 16);
            }
            *(uint4*)&lx[(r * 16 + (cx ^ (r & 7))) * 8] = packed;
        }
    }
    __syncthreads();

    const int wv = t >> 6, l = t & 63;
    const int row = wv * 16 + (l & 15);
    const int lg = l >> 4;
    f32x4 acc[8] = {};

    #pragma unroll
    for (int kb = 0; kb < 4; ++kb) {
        const int cx = kb * 4 + lg;
        bf16x8 a = *(const bf16x8*)&lx[(row * 16 + (cx ^ (row & 7))) * 8];
        #pragma unroll
        for (int nt = 0; nt < 8; ++nt) {
            const int n = nt * 16 + (l & 15);
            bf16x8 b = *(const bf16x8*)&lw[(n * 16 + (cx ^ (n & 7))) * 8];
            acc[nt] = __builtin_amdgcn_mfma_f32_16x16x32_bf16(a, b, acc[nt], 0, 0, 0);
        }
    }

    // C/D layout: col = lane&15, row = (lane>>4)*4 + reg
    #pragma unroll
    for (int reg = 0; reg < 4; ++reg) {
        const int grow = r0 + wv * 16 + lg * 4 + reg;
        if (grow < nrows) {
            #pragma unroll
            for (int nt = 0; nt < 8; ++nt)
                H[(size_t)grow * 128 + nt * 16 + (l & 15)] = f2bf(acc[nt][reg]);
        }
    }
}

// ---------------- attention dots from bf16 H ----------------
template <int HEADS_T>
__global__ __launch_bounds__(256) void att_dot(const ushort* __restrict__ H,
                                               const float* __restrict__ attS,
                                               const float* __restrict__ attD,
                                               float* __restrict__ aS,
                                               float* __restrict__ aD) {
    const int i = blockIdx.x * 256 + threadIdx.x;
    if (i >= N_NODES * HEADS_T) return;
    const int n = i / HEADS_T, h = i % HEADS_T;
    constexpr int HIDv = 128 / HEADS_T;
    const ushort* row = H + (size_t)n * 128 + h * HIDv;
    float sv = 0.f, dv = 0.f;
    for (int j = 0; j < HIDv; j += 8) {
        uint4 p = *(const uint4*)(row + j);
        uint w[4] = {p.x, p.y, p.z, p.w};
        #pragma unroll
        for (int q = 0; q < 4; ++q) {
            float e0 = bf2f(w[q] & 0xffffu);
            float e1 = bf2f(w[q] >> 16);
            sv += e0 * attS[h * HIDv + j + 2 * q] + e1 * attS[h * HIDv + j + 2 * q + 1];
            dv += e0 * attD[h * HIDv + j + 2 * q] + e1 * attD[h * HIDv + j + 2 * q + 1];
        }
    }
    aS[i] = sv;
    aD[i] = dv;
}

// ---------------- aggregation: one wave per dst node ----------------
// Layer 1: 8 heads x 16. Lane handles channels (2*lane, 2*lane+1); head = lane>>3.
__global__ __launch_bounds__(256) void agg8(const int* __restrict__ rowptr,
                                            const int* __restrict__ csrc,
                                            const float* __restrict__ aS,
                                            const float* __restrict__ aD,
                                            const ushort* __restrict__ Hm,
                                            const float* __restrict__ bias,
                                            float* __restrict__ out) {
    const int d = blockIdx.x * 4 + (threadIdx.x >> 6);
    const int lane = threadIdx.x & 63;
    const int hc = lane >> 3;                       // head of my channels
    const float adh = aD[d * 8 + (lane & 7)];       // for weight compute (head = lane&7)

    const int base = rowptr[d], end = rowptr[d + 1];
    float acc0 = 0.f, acc1 = 0.f, ws = 0.f;

    for (int c0 = base; c0 < end; c0 += 64) {
        const int rem = min(64, end - c0);
        const int s_l = (lane < rem) ? csrc[c0 + lane] : 0;
        for (int sub = 0; sub < rem; sub += 8) {
            // this lane computes weight for edge sub+(lane>>3), head lane&7
            const int s_w = __shfl(s_l, sub + (lane >> 3));
            const float w = __expf(lrelu(aS[s_w * 8 + (lane & 7)] + adh));
            const int m = min(8, rem - sub);
            for (int j = 0; j < m; ++j) {
                const int s = __shfl(s_l, sub + j);
                const float wj = __shfl(w, (j << 3) | hc);
                const uint p = *(const uint*)(Hm + (size_t)s * 128 + 2 * lane);
                acc0 += wj * bf2f(p & 0xffffu);
                acc1 += wj * bf2f(p >> 16);
                ws += wj;
            }
        }
    }
    const float inv = 1.f / (ws + EPS);
    float v0 = acc0 * inv + bias[2 * lane];
    float v1 = acc1 * inv + bias[2 * lane + 1];
    v0 = fmaxf(v0, 0.f);
    v1 = fmaxf(v1, 0.f);
    *(float2*)(out + (size_t)d * 128 + 2 * lane) = make_float2(v0, v1);
}

// Layer 2: single head. Final output fp32 (no relu).
__global__ __launch_bounds__(256) void agg1(const int* __restrict__ rowptr,
                                            const int* __restrict__ csrc,
                                            const float* __restrict__ aS,
                                            const float* __restrict__ aD,
                                            const ushort* __restrict__ Hm,
                                            const float* __restrict__ bias,
                                            float* __restrict__ out) {
    const int d = blockIdx.x * 4 + (threadIdx.x >> 6);
    const int lane = threadIdx.x & 63;
    const float ad = aD[d];

    const int base = rowptr[d], end = rowptr[d + 1];
    float acc0 = 0.f, acc1 = 0.f, ws = 0.f;

    for (int c0 = base; c0 < end; c0 += 64) {
        const int rem = min(64, end - c0);
        const int s_l = (lane < rem) ? csrc[c0 + lane] : 0;
        const float w_l = (lane < rem) ? __expf(lrelu(aS[s_l] + ad)) : 0.f;
        for (int j = 0; j < rem; ++j) {
            const int s = __shfl(s_l, j);
            const float w = __shfl(w_l, j);
            const uint p = *(const uint*)(Hm + (size_t)s * 128 + 2 * lane);
            acc0 += w * bf2f(p & 0xffffu);
            acc1 += w * bf2f(p >> 16);
            ws += w;
        }
    }
    const float inv = 1.f / (ws + EPS);
    const float v0 = acc0 * inv + bias[2 * lane];
    const float v1 = acc1 * inv + bias[2 * lane + 1];
    *(float2*)(out + (size_t)d * 128 + 2 * lane) = make_float2(v0, v1);
}

extern "C" void kernel_launch(void* const* d_in, const int* in_sizes, int n_in,
                              void* d_out, int out_size, void* d_ws, size_t ws_size,
                              hipStream_t stream) {
    const float* x        = (const float*)d_in[0];
    const int*   ei       = (const int*)  d_in[1];
    const float* W1       = (const float*)d_in[2];
    const float* att_src1 = (const float*)d_in[3];
    const float* att_dst1 = (const float*)d_in[4];
    const float* b1       = (const float*)d_in[5];
    const float* W2       = (const float*)d_in[6];
    const float* att_src2 = (const float*)d_in[7];
    const float* att_dst2 = (const float*)d_in[8];
    const float* b2       = (const float*)d_in[9];
    float* out = (float*)d_out;

    // Workspace layout
    ushort* Hbf = (ushort*)d_ws;                       // N*128 bf16
    float*  o1  = (float*)(Hbf + (size_t)N_NODES * 128); // N*128 fp32
    float*  aS1 = o1  + (size_t)N_NODES * 128;         // N*8
    float*  aD1 = aS1 + (size_t)N_NODES * 8;           // N*8
    float*  aS2 = aD1 + (size_t)N_NODES * 8;           // N
    float*  aD2 = aS2 + N_NODES;                       // N
    ushort* W1t = (ushort*)(aD2 + N_NODES);            // 128*128
    ushort* W2t = W1t + 128 * 128;                     // 128*128
    int* cnt    = (int*)(W2t + 128 * 128);             // N
    int* cursor = cnt + N_NODES;                       // N
    int* rowptr = cursor + N_NODES;                    // N+1
    int* bsum   = rowptr + N_NODES + 1;                // 128
    int* csrc   = bsum + 128;                          // ETOT + pad

    const int nblk = (N_NODES + 255) / 256;
    const int eblk = (ETOT + 255) / 256;
    const int gemm_blocks = (N_NODES + 63) / 64;       // 782
    const int agg_blocks = N_NODES / 4;                // 12500

    // CSR build (graph identical for both layers)
    convert_W<<<2, 256, 0, stream>>>(W1, W2, W1t, W2t);
    zero_counts<<<nblk, 256, 0, stream>>>(cnt, cursor);
    count_kernel<<<eblk, 256, 0, stream>>>(ei, cnt);
    block_sums<<<NBLK_SCAN, SCAN_BLK, 0, stream>>>(cnt, bsum);
    scan98<<<1, 128, 0, stream>>>(bsum);
    scan_final<<<NBLK_SCAN, SCAN_BLK, 0, stream>>>(cnt, bsum, rowptr);
    scatter_kernel<<<eblk, 256, 0, stream>>>(ei, rowptr, cursor, csrc);

    // Layer 1
    mfma_gemm<<<gemm_blocks, 256, 0, stream>>>(x, W1t, Hbf, N_NODES);
    att_dot<8><<<(N_NODES * 8 + 255) / 256, 256, 0, stream>>>(Hbf, att_src1, att_dst1, aS1, aD1);
    agg8<<<agg_blocks, 256, 0, stream>>>(rowptr, csrc, aS1, aD1, Hbf, b1, o1);

    // Layer 2
    mfma_gemm<<<gemm_blocks, 256, 0, stream>>>(o1, W2t, Hbf, N_NODES);
    att_dot<1><<<(N_NODES + 255) / 256, 256, 0, stream>>>(Hbf, att_src2, att_dst2, aS2, aD2);
    agg1<<<agg_blocks, 256, 0, stream>>>(rowptr, csrc, aS2, aD2, Hbf, b2, out);
}

// Round 4
// 218.843 us; speedup vs baseline: 4.1153x; 1.2155x over previous
//
#include <hip/hip_runtime.h>

// GraphGATNet 2-layer GAT. Round 4:
//  - agg: 16-lane x uint4 row gather (4 edges per wave-load), LDS weight table,
//    1-deep prefetch, shfl_xor group reduction. (was: 1 edge/iter, 4B/lane, serial)
//  - att1 dots fused into GEMM1 epilogue; att2 dots fused into agg8 epilogue via
//    a2 = relu(o1) . (W2 @ att2)  (precomputed 128-vectors vs, vd)
//  - o1 stored bf16 (same rounding GEMM2 staging applied anyway) -> half traffic
//  - CSR build unchanged

constexpr int N_NODES = 50000;
constexpr int E_EDGES = 800000;
constexpr int ETOT = E_EDGES + N_NODES;
constexpr float NEG_SLOPE = 0.2f;
constexpr float EPS = 1e-16f;
constexpr int SCAN_BLK = 512;
constexpr int NBLK_SCAN = (N_NODES + SCAN_BLK - 1) / SCAN_BLK;   // 98

typedef short bf16x8 __attribute__((ext_vector_type(8)));
typedef float f32x4 __attribute__((ext_vector_type(4)));

__device__ __forceinline__ float lrelu(float x) { return x > 0.f ? x : NEG_SLOPE * x; }
__device__ __forceinline__ ushort f2bf(float f) {
    uint u = __float_as_uint(f);
    return (ushort)((u + 0x7fffu + ((u >> 16) & 1u)) >> 16);
}
__device__ __forceinline__ float bf2f(uint u) { return __uint_as_float(u << 16); }

__device__ __forceinline__ void fma8(float* acc, uint4 p, float w, float& ws) {
    ws += w;
    acc[0] += w * bf2f(p.x & 0xffffu); acc[1] += w * bf2f(p.x >> 16);
    acc[2] += w * bf2f(p.y & 0xffffu); acc[3] += w * bf2f(p.y >> 16);
    acc[4] += w * bf2f(p.z & 0xffffu); acc[5] += w * bf2f(p.z >> 16);
    acc[6] += w * bf2f(p.w & 0xffffu); acc[7] += w * bf2f(p.w >> 16);
}

// ---------------- CSR build ----------------
__global__ __launch_bounds__(256) void zero_counts(int* cnt, int* cursor) {
    int i = blockIdx.x * blockDim.x + threadIdx.x;
    if (i < N_NODES) { cnt[i] = 0; cursor[i] = 0; }
}

__global__ __launch_bounds__(256) void count_kernel(const int* __restrict__ ei,
                                                    int* __restrict__ cnt) {
    int e = blockIdx.x * blockDim.x + threadIdx.x;
    if (e >= ETOT) return;
    int d = (e < E_EDGES) ? ei[E_EDGES + e] : (e - E_EDGES);
    atomicAdd(&cnt[d], 1);
}

__global__ __launch_bounds__(SCAN_BLK) void block_sums(const int* __restrict__ cnt,
                                                       int* __restrict__ bsum) {
    __shared__ int sm[SCAN_BLK];
    int i = blockIdx.x * SCAN_BLK + threadIdx.x;
    sm[threadIdx.x] = (i < N_NODES) ? cnt[i] : 0;
    __syncthreads();
    for (int off = SCAN_BLK / 2; off > 0; off >>= 1) {
        if (threadIdx.x < off) sm[threadIdx.x] += sm[threadIdx.x + off];
        __syncthreads();
    }
    if (threadIdx.x == 0) bsum[blockIdx.x] = sm[0];
}

__global__ __launch_bounds__(128) void scan98(int* bsum) {   // exclusive scan, 98 vals
    __shared__ int sm[128];
    int t = threadIdx.x;
    int v = (t < NBLK_SCAN) ? bsum[t] : 0;
    sm[t] = v;
    __syncthreads();
    for (int off = 1; off < 128; off <<= 1) {
        int x = (t >= off) ? sm[t - off] : 0;
        __syncthreads();
        sm[t] += x;
        __syncthreads();
    }
    if (t < NBLK_SCAN) bsum[t] = sm[t] - v;
}

__global__ __launch_bounds__(SCAN_BLK) void scan_final(const int* __restrict__ cnt,
                                                       const int* __restrict__ bsum,
                                                       int* __restrict__ rowptr) {
    __shared__ int sm[SCAN_BLK];
    int i = blockIdx.x * SCAN_BLK + threadIdx.x;
    int v = (i < N_NODES) ? cnt[i] : 0;
    sm[threadIdx.x] = v;
    __syncthreads();
    for (int off = 1; off < SCAN_BLK; off <<= 1) {
        int t = (threadIdx.x >= off) ? sm[threadIdx.x - off] : 0;
        __syncthreads();
        sm[threadIdx.x] += t;
        __syncthreads();
    }
    if (i < N_NODES) rowptr[i] = bsum[blockIdx.x] + sm[threadIdx.x] - v;
    if (blockIdx.x == 0 && threadIdx.x == 0) rowptr[N_NODES] = ETOT;
}

__global__ __launch_bounds__(256) void scatter_kernel(const int* __restrict__ ei,
                                                      const int* __restrict__ rowptr,
                                                      int* __restrict__ cursor,
                                                      int* __restrict__ csrc) {
    int e = blockIdx.x * blockDim.x + threadIdx.x;
    if (e >= ETOT) return;
    int s, d;
    if (e < E_EDGES) { s = ei[e]; d = ei[E_EDGES + e]; }
    else             { s = d = e - E_EDGES; }
    int pos = rowptr[d] + atomicAdd(&cursor[d], 1);
    csrc[pos] = s;
}

// ---------------- W -> bf16 transposed, + vs/vd = W2 @ att2 ----------------
__global__ __launch_bounds__(256) void convert_W(const float* __restrict__ W1,
                                                 const float* __restrict__ W2,
                                                 const float* __restrict__ attS2,
                                                 const float* __restrict__ attD2,
                                                 ushort* __restrict__ W1t,
                                                 ushort* __restrict__ W2t,
                                                 float* __restrict__ vs,
                                                 float* __restrict__ vd) {
    const float* W = (blockIdx.x == 0) ? W1 : W2;
    ushort* Wt = (blockIdx.x == 0) ? W1t : W2t;
    const int t = threadIdx.x;
    const int n = t >> 1, k0 = (t & 1) * 64;
    for (int k = 0; k < 64; k += 2) {
        uint lo = f2bf(W[(size_t)(k0 + k) * 128 + n]);
        uint hi = f2bf(W[(size_t)(k0 + k + 1) * 128 + n]);
        *(uint*)&Wt[(size_t)n * 128 + k0 + k] = lo | (hi << 16);
    }
    if (blockIdx.x == 1) {
        const int k = t & 127;
        const float* av = (t < 128) ? attS2 : attD2;
        float* dst = (t < 128) ? vs : vd;
        float s = 0.f;
        for (int c = 0; c < 128; ++c) s += W2[(size_t)k * 128 + c] * av[c];
        dst[k] = s;
    }
}

// ---------------- MFMA GEMM: H(bf16) = X @ W, tile 64x128x128 ----------------
// ATT8: fused layer-1 attention dots from the fp32 accumulator tile.
template <bool BF16IN, bool ATT8>
__global__ __launch_bounds__(256) void mfma_gemm(const void* __restrict__ Xv,
                                                 const ushort* __restrict__ Wt,
                                                 ushort* __restrict__ H,
                                                 const float* __restrict__ attS,
                                                 const float* __restrict__ attD,
                                                 float* __restrict__ aS,
                                                 float* __restrict__ aD,
                                                 int nrows) {
    __shared__ __align__(16) char smem[16384 + 32768];
    ushort* lx = (ushort*)smem;            // 64 x 128 bf16 (swizzled)
    ushort* lw = (ushort*)(smem + 16384);  // 128 x 128 bf16 (swizzled)
    float*  hs = (float*)smem;             // epilogue alias: 64 x 130 f32

    const int t = threadIdx.x;
    const int r0 = blockIdx.x * 64;

    // stage W
    {
        const int n = t >> 1, half = t & 1;
        const ushort* src = Wt + (size_t)n * 128 + half * 64;
        #pragma unroll
        for (int c = 0; c < 8; ++c) {
            int cx = half * 8 + c;
            uint4 v = *(const uint4*)(src + c * 8);
            *(uint4*)&lw[(n * 16 + (cx ^ (n & 7))) * 8] = v;
        }
    }
    // stage X
    {
        const int r = t >> 2, q = t & 3;
        const int grow = r0 + r;
        const uint4 z = {0, 0, 0, 0};
        #pragma unroll
        for (int cc = 0; cc < 4; ++cc) {
            int cx = q * 4 + cc;
            uint4 packed = z;
            if (grow < nrows) {
                if (BF16IN) {
                    packed = *(const uint4*)((const ushort*)Xv + (size_t)grow * 128 + cx * 8);
                } else {
                    const float* X = (const float*)Xv;
                    const float4 f0 = *(const float4*)(X + (size_t)grow * 128 + cx * 8);
                    const float4 f1 = *(const float4*)(X + (size_t)grow * 128 + cx * 8 + 4);
                    packed.x = (uint)f2bf(f0.x) | ((uint)f2bf(f0.y) << 16);
                    packed.y = (uint)f2bf(f0.z) | ((uint)f2bf(f0.w) << 16);
                    packed.z = (uint)f2bf(f1.x) | ((uint)f2bf(f1.y) << 16);
                    packed.w = (uint)f2bf(f1.z) | ((uint)f2bf(f1.w) << 16);
                }
            }
            *(uint4*)&lx[(r * 16 + (cx ^ (r & 7))) * 8] = packed;
        }
    }
    __syncthreads();

    const int wv = t >> 6, l = t & 63;
    const int row = wv * 16 + (l & 15);
    const int lg = l >> 4;
    f32x4 acc[8] = {};

    #pragma unroll
    for (int kb = 0; kb < 4; ++kb) {
        const int cx = kb * 4 + lg;
        bf16x8 a = *(const bf16x8*)&lx[(row * 16 + (cx ^ (row & 7))) * 8];
        #pragma unroll
        for (int nt = 0; nt < 8; ++nt) {
            const int n = nt * 16 + (l & 15);
            bf16x8 b = *(const bf16x8*)&lw[(n * 16 + (cx ^ (n & 7))) * 8];
            acc[nt] = __builtin_amdgcn_mfma_f32_16x16x32_bf16(a, b, acc[nt], 0, 0, 0);
        }
    }

    // C/D layout: col = lane&15, row = (lane>>4)*4 + reg
    #pragma unroll
    for (int reg = 0; reg < 4; ++reg) {
        const int grow = r0 + wv * 16 + lg * 4 + reg;
        if (grow < nrows) {
            #pragma unroll
            for (int nt = 0; nt < 8; ++nt)
                H[(size_t)grow * 128 + nt * 16 + (l & 15)] = f2bf(acc[nt][reg]);
        }
    }

    if (ATT8) {
        __syncthreads();   // all MFMA LDS reads done; safe to overwrite as hs
        #pragma unroll
        for (int reg = 0; reg < 4; ++reg) {
            const int r = wv * 16 + lg * 4 + reg;
            #pragma unroll
            for (int nt = 0; nt < 8; ++nt)
                hs[r * 130 + nt * 16 + (l & 15)] = acc[nt][reg];
        }
        __syncthreads();
        for (int q = t; q < 512; q += 256) {
            const int r = q >> 3, h = q & 7;
            if (r0 + r < nrows) {
                float sv = 0.f, dv = 0.f;
                #pragma unroll
                for (int j = 0; j < 16; ++j) {
                    const float hv = hs[r * 130 + h * 16 + j];
                    sv += hv * attS[h * 16 + j];
                    dv += hv * attD[h * 16 + j];
                }
                aS[(size_t)(r0 + r) * 8 + h] = sv;
                aD[(size_t)(r0 + r) * 8 + h] = dv;
            }
        }
    }
}

// ---------------- agg layer 1: wave per dst, 4 edges per load ----------------
// lane = 16*g + i : group g handles edge 4t+g, lane covers channels [8i, 8i+8)
__global__ __launch_bounds__(256) void agg8(const int* __restrict__ rowptr,
                                            const int* __restrict__ csrc,
                                            const float* __restrict__ aS,
                                            const float* __restrict__ aD,
                                            const ushort* __restrict__ Hm,
                                            const float* __restrict__ bias,
                                            const float* __restrict__ vs,
                                            const float* __restrict__ vd,
                                            ushort* __restrict__ o1bf,
                                            float* __restrict__ aS2,
                                            float* __restrict__ aD2) {
    __shared__ float wlds[4][512];
    const int wv = threadIdx.x >> 6;
    const int d = blockIdx.x * 4 + wv;
    const int lane = threadIdx.x & 63;
    const int g = lane >> 4, i = lane & 15, hc = i >> 1;
    const int hw = lane & 7;
    const float adh = aD[(size_t)d * 8 + hw];

    const int base = rowptr[d], end = rowptr[d + 1];
    float acc[8] = {0.f, 0.f, 0.f, 0.f, 0.f, 0.f, 0.f, 0.f};
    float ws = 0.f;
    const uint4 zero4 = {0, 0, 0, 0};

    for (int c0 = base; c0 < end; c0 += 64) {
        const int rem = min(64, end - c0);
        const int s_l = (lane < rem) ? csrc[c0 + lane] : 0;

        // weight table for this chunk: wlds[wv][j*8+h]
        const int nwc = (rem + 7) >> 3;
        for (int jj = 0; jj < nwc; ++jj) {
            const int j = jj * 8 + (lane >> 3);
            const int sj = __shfl(s_l, j);
            float w = 0.f;
            if (j < rem) w = __expf(lrelu(aS[(size_t)sj * 8 + hw] + adh));
            wlds[wv][j * 8 + hw] = w;
        }

        // gather: 4 edges per iteration, prefetch next 4 rows
        const int niter = (rem + 3) >> 2;
        int j = g;
        int scur = __shfl(s_l, j);
        uint4 pcur = zero4;
        if (j < rem) pcur = *(const uint4*)(Hm + (size_t)scur * 128 + i * 8);
        for (int tt = 0; tt < niter; ++tt) {
            const int jn = j + 4;
            const int snxt = __shfl(s_l, jn & 63);
            uint4 pnxt = zero4;
            if (jn < rem) pnxt = *(const uint4*)(Hm + (size_t)snxt * 128 + i * 8);
            float w = 0.f;
            if (j < rem) w = wlds[wv][j * 8 + hc];
            fma8(acc, pcur, w, ws);
            pcur = pnxt;
            j = jn;
        }
    }

    #pragma unroll
    for (int k = 0; k < 8; ++k) {
        acc[k] += __shfl_xor(acc[k], 16);
        acc[k] += __shfl_xor(acc[k], 32);
    }
    ws += __shfl_xor(ws, 16);
    ws += __shfl_xor(ws, 32);

    const float inv = 1.f / (ws + EPS);
    float v[8];
    #pragma unroll
    for (int k = 0; k < 8; ++k) v[k] = fmaxf(acc[k] * inv + bias[i * 8 + k], 0.f);

    // fused layer-2 attention dots: a2 = v . (W2 @ att2)
    float ps = 0.f, pd = 0.f;
    #pragma unroll
    for (int k = 0; k < 8; ++k) { ps += v[k] * vs[i * 8 + k]; pd += v[k] * vd[i * 8 + k]; }
    #pragma unroll
    for (int off = 1; off <= 8; off <<= 1) {
        ps += __shfl_xor(ps, off);
        pd += __shfl_xor(pd, off);
    }
    if (lane == 0) { aS2[d] = ps; aD2[d] = pd; }

    if (g == 0) {
        uint4 pk;
        pk.x = (uint)f2bf(v[0]) | ((uint)f2bf(v[1]) << 16);
        pk.y = (uint)f2bf(v[2]) | ((uint)f2bf(v[3]) << 16);
        pk.z = (uint)f2bf(v[4]) | ((uint)f2bf(v[5]) << 16);
        pk.w = (uint)f2bf(v[6]) | ((uint)f2bf(v[7]) << 16);
        *(uint4*)(o1bf + (size_t)d * 128 + i * 8) = pk;
    }
}

// ---------------- agg layer 2: single head ----------------
__global__ __launch_bounds__(256) void agg1(const int* __restrict__ rowptr,
                                            const int* __restrict__ csrc,
                                            const float* __restrict__ aS,
                                            const float* __restrict__ aD,
                                            const ushort* __restrict__ Hm,
                                            const float* __restrict__ bias,
                                            float* __restrict__ out) {
    const int wv = threadIdx.x >> 6;
    const int d = blockIdx.x * 4 + wv;
    const int lane = threadIdx.x & 63;
    const int g = lane >> 4, i = lane & 15;
    const float ad = aD[d];

    const int base = rowptr[d], end = rowptr[d + 1];
    float acc[8] = {0.f, 0.f, 0.f, 0.f, 0.f, 0.f, 0.f, 0.f};
    float ws = 0.f;
    const uint4 zero4 = {0, 0, 0, 0};

    for (int c0 = base; c0 < end; c0 += 64) {
        const int rem = min(64, end - c0);
        const int s_l = (lane < rem) ? csrc[c0 + lane] : 0;
        const float w_l = (lane < rem) ? __expf(lrelu(aS[s_l] + ad)) : 0.f;

        const int niter = (rem + 3) >> 2;
        int j = g;
        int scur = __shfl(s_l, j);
        float wcur = __shfl(w_l, j);
        uint4 pcur = zero4;
        if (j < rem) pcur = *(const uint4*)(Hm + (size_t)scur * 128 + i * 8);
        for (int tt = 0; tt < niter; ++tt) {
            const int jn = j + 4;
            const int snxt = __shfl(s_l, jn & 63);
            const float wnxt = __shfl(w_l, jn & 63);
            uint4 pnxt = zero4;
            if (jn < rem) pnxt = *(const uint4*)(Hm + (size_t)snxt * 128 + i * 8);
            fma8(acc, pcur, wcur, ws);
            pcur = pnxt;
            wcur = wnxt;
            j = jn;
        }
    }

    #pragma unroll
    for (int k = 0; k < 8; ++k) {
        acc[k] += __shfl_xor(acc[k], 16);
        acc[k] += __shfl_xor(acc[k], 32);
    }
    ws += __shfl_xor(ws, 16);
    ws += __shfl_xor(ws, 32);

    if (g == 0) {
        const float inv = 1.f / (ws + EPS);
        float4 o0, o1v;
        o0.x = acc[0] * inv + bias[i * 8 + 0];
        o0.y = acc[1] * inv + bias[i * 8 + 1];
        o0.z = acc[2] * inv + bias[i * 8 + 2];
        o0.w = acc[3] * inv + bias[i * 8 + 3];
        o1v.x = acc[4] * inv + bias[i * 8 + 4];
        o1v.y = acc[5] * inv + bias[i * 8 + 5];
        o1v.z = acc[6] * inv + bias[i * 8 + 6];
        o1v.w = acc[7] * inv + bias[i * 8 + 7];
        *(float4*)(out + (size_t)d * 128 + i * 8) = o0;
        *(float4*)(out + (size_t)d * 128 + i * 8 + 4) = o1v;
    }
}

extern "C" void kernel_launch(void* const* d_in, const int* in_sizes, int n_in,
                              void* d_out, int out_size, void* d_ws, size_t ws_size,
                              hipStream_t stream) {
    const float* x        = (const float*)d_in[0];
    const int*   ei       = (const int*)  d_in[1];
    const float* W1       = (const float*)d_in[2];
    const float* att_src1 = (const float*)d_in[3];
    const float* att_dst1 = (const float*)d_in[4];
    const float* b1       = (const float*)d_in[5];
    const float* W2       = (const float*)d_in[6];
    const float* att_src2 = (const float*)d_in[7];
    const float* att_dst2 = (const float*)d_in[8];
    const float* b2       = (const float*)d_in[9];
    float* out = (float*)d_out;

    // Workspace layout
    ushort* Hbf  = (ushort*)d_ws;                          // N*128 bf16 (h1, then h2)
    ushort* o1bf = Hbf + (size_t)N_NODES * 128;            // N*128 bf16
    float*  aS1  = (float*)(o1bf + (size_t)N_NODES * 128); // N*8
    float*  aD1  = aS1 + (size_t)N_NODES * 8;              // N*8
    float*  aS2  = aD1 + (size_t)N_NODES * 8;              // N
    float*  aD2  = aS2 + N_NODES;                          // N
    float*  vs   = aD2 + N_NODES;                          // 128
    float*  vd   = vs + 128;                               // 128
    ushort* W1t  = (ushort*)(vd + 128);                    // 128*128
    ushort* W2t  = W1t + 128 * 128;                        // 128*128
    int* cnt     = (int*)(W2t + 128 * 128);                // N
    int* cursor  = cnt + N_NODES;                          // N
    int* rowptr  = cursor + N_NODES;                       // N+1
    int* bsum    = rowptr + N_NODES + 1;                   // 128
    int* csrc    = bsum + 128;                             // ETOT

    const int nblk = (N_NODES + 255) / 256;
    const int eblk = (ETOT + 255) / 256;
    const int gemm_blocks = (N_NODES + 63) / 64;           // 782
    const int agg_blocks = N_NODES / 4;                    // 12500

    convert_W<<<2, 256, 0, stream>>>(W1, W2, att_src2, att_dst2, W1t, W2t, vs, vd);
    zero_counts<<<nblk, 256, 0, stream>>>(cnt, cursor);
    count_kernel<<<eblk, 256, 0, stream>>>(ei, cnt);
    block_sums<<<NBLK_SCAN, SCAN_BLK, 0, stream>>>(cnt, bsum);
    scan98<<<1, 128, 0, stream>>>(bsum);
    scan_final<<<NBLK_SCAN, SCAN_BLK, 0, stream>>>(cnt, bsum, rowptr);
    scatter_kernel<<<eblk, 256, 0, stream>>>(ei, rowptr, cursor, csrc);

    // Layer 1
    mfma_gemm<false, true><<<gemm_blocks, 256, 0, stream>>>(
        x, W1t, Hbf, att_src1, att_dst1, aS1, aD1, N_NODES);
    agg8<<<agg_blocks, 256, 0, stream>>>(
        rowptr, csrc, aS1, aD1, Hbf, b1, vs, vd, o1bf, aS2, aD2);

    // Layer 2
    mfma_gemm<true, false><<<gemm_blocks, 256, 0, stream>>>(
        o1bf, W2t, Hbf, nullptr, nullptr, nullptr, nullptr, N_NODES);
    agg1<<<agg_blocks, 256, 0, stream>>>(
        rowptr, csrc, aS2, aD2, Hbf, b2, out);
}

// Round 5
// 208.322 us; speedup vs baseline: 4.3232x; 1.0505x over previous
//
#include <hip/hip_runtime.h>

// GraphGATNet 2-layer GAT. Round 5:
//  - CSR build: count pass captures rank via atomicAdd return (packed 2x16-bit
//    counts per word); scatter becomes atomic-free (pos = rowptr[d] + rank[e])
//    with nontemporal store. Cursor array + one 850K-atomic pass deleted.
//    (R4: scatter_kernel was #1 at 51-55us, atomic+write-allocate bound)
//  - everything else unchanged from R4 (MFMA GEMMs with fused att dots,
//    16-lane x uint4 gather agg, bf16 H/o1)

constexpr int N_NODES = 50000;
constexpr int E_EDGES = 800000;
constexpr int ETOT = E_EDGES + N_NODES;
constexpr float NEG_SLOPE = 0.2f;
constexpr float EPS = 1e-16f;
constexpr int SCAN_BLK = 512;
constexpr int NBLK_SCAN = (N_NODES + SCAN_BLK - 1) / SCAN_BLK;   // 98

typedef short bf16x8 __attribute__((ext_vector_type(8)));
typedef float f32x4 __attribute__((ext_vector_type(4)));

__device__ __forceinline__ float lrelu(float x) { return x > 0.f ? x : NEG_SLOPE * x; }
__device__ __forceinline__ ushort f2bf(float f) {
    uint u = __float_as_uint(f);
    return (ushort)((u + 0x7fffu + ((u >> 16) & 1u)) >> 16);
}
__device__ __forceinline__ float bf2f(uint u) { return __uint_as_float(u << 16); }

__device__ __forceinline__ void fma8(float* acc, uint4 p, float w, float& ws) {
    ws += w;
    acc[0] += w * bf2f(p.x & 0xffffu); acc[1] += w * bf2f(p.x >> 16);
    acc[2] += w * bf2f(p.y & 0xffffu); acc[3] += w * bf2f(p.y >> 16);
    acc[4] += w * bf2f(p.z & 0xffffu); acc[5] += w * bf2f(p.z >> 16);
    acc[6] += w * bf2f(p.w & 0xffffu); acc[7] += w * bf2f(p.w >> 16);
}

// ---------------- CSR build ----------------
__global__ __launch_bounds__(256) void zero_counts(uint* cnt16) {
    int i = blockIdx.x * blockDim.x + threadIdx.x;
    if (i < (N_NODES + 1) / 2) cnt16[i] = 0;
}

// count + rank in one pass: rank[e] = arrival index of edge e within its dst bucket
__global__ __launch_bounds__(256) void count_rank(const int* __restrict__ ei,
                                                  uint* __restrict__ cnt16,
                                                  ushort* __restrict__ rank) {
    int e = blockIdx.x * blockDim.x + threadIdx.x;
    if (e >= ETOT) return;
    int d = (e < E_EDGES) ? ei[E_EDGES + e] : (e - E_EDGES);
    const uint shift = (d & 1) * 16;
    uint old = atomicAdd(&cnt16[d >> 1], 1u << shift);
    rank[e] = (ushort)((old >> shift) & 0xffffu);
}

__device__ __forceinline__ uint cnt_at(const uint* cnt16, int i) {
    return (cnt16[i >> 1] >> ((i & 1) * 16)) & 0xffffu;
}

__global__ __launch_bounds__(SCAN_BLK) void block_sums(const uint* __restrict__ cnt16,
                                                       int* __restrict__ bsum) {
    __shared__ int sm[SCAN_BLK];
    int i = blockIdx.x * SCAN_BLK + threadIdx.x;
    sm[threadIdx.x] = (i < N_NODES) ? (int)cnt_at(cnt16, i) : 0;
    __syncthreads();
    for (int off = SCAN_BLK / 2; off > 0; off >>= 1) {
        if (threadIdx.x < off) sm[threadIdx.x] += sm[threadIdx.x + off];
        __syncthreads();
    }
    if (threadIdx.x == 0) bsum[blockIdx.x] = sm[0];
}

__global__ __launch_bounds__(128) void scan98(int* bsum) {   // exclusive scan, 98 vals
    __shared__ int sm[128];
    int t = threadIdx.x;
    int v = (t < NBLK_SCAN) ? bsum[t] : 0;
    sm[t] = v;
    __syncthreads();
    for (int off = 1; off < 128; off <<= 1) {
        int x = (t >= off) ? sm[t - off] : 0;
        __syncthreads();
        sm[t] += x;
        __syncthreads();
    }
    if (t < NBLK_SCAN) bsum[t] = sm[t] - v;
}

__global__ __launch_bounds__(SCAN_BLK) void scan_final(const uint* __restrict__ cnt16,
                                                       const int* __restrict__ bsum,
                                                       int* __restrict__ rowptr) {
    __shared__ int sm[SCAN_BLK];
    int i = blockIdx.x * SCAN_BLK + threadIdx.x;
    int v = (i < N_NODES) ? (int)cnt_at(cnt16, i) : 0;
    sm[threadIdx.x] = v;
    __syncthreads();
    for (int off = 1; off < SCAN_BLK; off <<= 1) {
        int t = (threadIdx.x >= off) ? sm[threadIdx.x - off] : 0;
        __syncthreads();
        sm[threadIdx.x] += t;
        __syncthreads();
    }
    if (i < N_NODES) rowptr[i] = bsum[blockIdx.x] + sm[threadIdx.x] - v;
    if (blockIdx.x == 0 && threadIdx.x == 0) rowptr[N_NODES] = ETOT;
}

// atomic-free scatter
__global__ __launch_bounds__(256) void scatter_kernel(const int* __restrict__ ei,
                                                      const int* __restrict__ rowptr,
                                                      const ushort* __restrict__ rank,
                                                      int* __restrict__ csrc) {
    int e = blockIdx.x * blockDim.x + threadIdx.x;
    if (e >= ETOT) return;
    int s, d;
    if (e < E_EDGES) { s = ei[e]; d = ei[E_EDGES + e]; }
    else             { s = d = e - E_EDGES; }
    const int pos = rowptr[d] + (int)rank[e];
    __builtin_nontemporal_store(s, &csrc[pos]);
}

// ---------------- W -> bf16 transposed, + vs/vd = W2 @ att2 ----------------
__global__ __launch_bounds__(256) void convert_W(const float* __restrict__ W1,
                                                 const float* __restrict__ W2,
                                                 const float* __restrict__ attS2,
                                                 const float* __restrict__ attD2,
                                                 ushort* __restrict__ W1t,
                                                 ushort* __restrict__ W2t,
                                                 float* __restrict__ vs,
                                                 float* __restrict__ vd) {
    const float* W = (blockIdx.x == 0) ? W1 : W2;
    ushort* Wt = (blockIdx.x == 0) ? W1t : W2t;
    const int t = threadIdx.x;
    const int n = t >> 1, k0 = (t & 1) * 64;
    for (int k = 0; k < 64; k += 2) {
        uint lo = f2bf(W[(size_t)(k0 + k) * 128 + n]);
        uint hi = f2bf(W[(size_t)(k0 + k + 1) * 128 + n]);
        *(uint*)&Wt[(size_t)n * 128 + k0 + k] = lo | (hi << 16);
    }
    if (blockIdx.x == 1) {
        const int k = t & 127;
        const float* av = (t < 128) ? attS2 : attD2;
        float* dst = (t < 128) ? vs : vd;
        float s = 0.f;
        for (int c = 0; c < 128; ++c) s += W2[(size_t)k * 128 + c] * av[c];
        dst[k] = s;
    }
}

// ---------------- MFMA GEMM: H(bf16) = X @ W, tile 64x128x128 ----------------
template <bool BF16IN, bool ATT8>
__global__ __launch_bounds__(256) void mfma_gemm(const void* __restrict__ Xv,
                                                 const ushort* __restrict__ Wt,
                                                 ushort* __restrict__ H,
                                                 const float* __restrict__ attS,
                                                 const float* __restrict__ attD,
                                                 float* __restrict__ aS,
                                                 float* __restrict__ aD,
                                                 int nrows) {
    __shared__ __align__(16) char smem[16384 + 32768];
    ushort* lx = (ushort*)smem;            // 64 x 128 bf16 (swizzled)
    ushort* lw = (ushort*)(smem + 16384);  // 128 x 128 bf16 (swizzled)
    float*  hs = (float*)smem;             // epilogue alias: 64 x 130 f32

    const int t = threadIdx.x;
    const int r0 = blockIdx.x * 64;

    // stage W
    {
        const int n = t >> 1, half = t & 1;
        const ushort* src = Wt + (size_t)n * 128 + half * 64;
        #pragma unroll
        for (int c = 0; c < 8; ++c) {
            int cx = half * 8 + c;
            uint4 v = *(const uint4*)(src + c * 8);
            *(uint4*)&lw[(n * 16 + (cx ^ (n & 7))) * 8] = v;
        }
    }
    // stage X
    {
        const int r = t >> 2, q = t & 3;
        const int grow = r0 + r;
        const uint4 z = {0, 0, 0, 0};
        #pragma unroll
        for (int cc = 0; cc < 4; ++cc) {
            int cx = q * 4 + cc;
            uint4 packed = z;
            if (grow < nrows) {
                if (BF16IN) {
                    packed = *(const uint4*)((const ushort*)Xv + (size_t)grow * 128 + cx * 8);
                } else {
                    const float* X = (const float*)Xv;
                    const float4 f0 = *(const float4*)(X + (size_t)grow * 128 + cx * 8);
                    const float4 f1 = *(const float4*)(X + (size_t)grow * 128 + cx * 8 + 4);
                    packed.x = (uint)f2bf(f0.x) | ((uint)f2bf(f0.y) << 16);
                    packed.y = (uint)f2bf(f0.z) | ((uint)f2bf(f0.w) << 16);
                    packed.z = (uint)f2bf(f1.x) | ((uint)f2bf(f1.y) << 16);
                    packed.w = (uint)f2bf(f1.z) | ((uint)f2bf(f1.w) << 16);
                }
            }
            *(uint4*)&lx[(r * 16 + (cx ^ (r & 7))) * 8] = packed;
        }
    }
    __syncthreads();

    const int wv = t >> 6, l = t & 63;
    const int row = wv * 16 + (l & 15);
    const int lg = l >> 4;
    f32x4 acc[8] = {};

    #pragma unroll
    for (int kb = 0; kb < 4; ++kb) {
        const int cx = kb * 4 + lg;
        bf16x8 a = *(const bf16x8*)&lx[(row * 16 + (cx ^ (row & 7))) * 8];
        #pragma unroll
        for (int nt = 0; nt < 8; ++nt) {
            const int n = nt * 16 + (l & 15);
            bf16x8 b = *(const bf16x8*)&lw[(n * 16 + (cx ^ (n & 7))) * 8];
            acc[nt] = __builtin_amdgcn_mfma_f32_16x16x32_bf16(a, b, acc[nt], 0, 0, 0);
        }
    }

    // C/D layout: col = lane&15, row = (lane>>4)*4 + reg
    #pragma unroll
    for (int reg = 0; reg < 4; ++reg) {
        const int grow = r0 + wv * 16 + lg * 4 + reg;
        if (grow < nrows) {
            #pragma unroll
            for (int nt = 0; nt < 8; ++nt)
                H[(size_t)grow * 128 + nt * 16 + (l & 15)] = f2bf(acc[nt][reg]);
        }
    }

    if (ATT8) {
        __syncthreads();   // all MFMA LDS reads done; safe to overwrite as hs
        #pragma unroll
        for (int reg = 0; reg < 4; ++reg) {
            const int r = wv * 16 + lg * 4 + reg;
            #pragma unroll
            for (int nt = 0; nt < 8; ++nt)
                hs[r * 130 + nt * 16 + (l & 15)] = acc[nt][reg];
        }
        __syncthreads();
        for (int q = t; q < 512; q += 256) {
            const int r = q >> 3, h = q & 7;
            if (r0 + r < nrows) {
                float sv = 0.f, dv = 0.f;
                #pragma unroll
                for (int j = 0; j < 16; ++j) {
                    const float hv = hs[r * 130 + h * 16 + j];
                    sv += hv * attS[h * 16 + j];
                    dv += hv * attD[h * 16 + j];
                }
                aS[(size_t)(r0 + r) * 8 + h] = sv;
                aD[(size_t)(r0 + r) * 8 + h] = dv;
            }
        }
    }
}

// ---------------- agg layer 1: wave per dst, 4 edges per load ----------------
__global__ __launch_bounds__(256) void agg8(const int* __restrict__ rowptr,
                                            const int* __restrict__ csrc,
                                            const float* __restrict__ aS,
                                            const float* __restrict__ aD,
                                            const ushort* __restrict__ Hm,
                                            const float* __restrict__ bias,
                                            const float* __restrict__ vs,
                                            const float* __restrict__ vd,
                                            ushort* __restrict__ o1bf,
                                            float* __restrict__ aS2,
                                            float* __restrict__ aD2) {
    __shared__ float wlds[4][512];
    const int wv = threadIdx.x >> 6;
    const int d = blockIdx.x * 4 + wv;
    const int lane = threadIdx.x & 63;
    const int g = lane >> 4, i = lane & 15, hc = i >> 1;
    const int hw = lane & 7;
    const float adh = aD[(size_t)d * 8 + hw];

    const int base = rowptr[d], end = rowptr[d + 1];
    float acc[8] = {0.f, 0.f, 0.f, 0.f, 0.f, 0.f, 0.f, 0.f};
    float ws = 0.f;
    const uint4 zero4 = {0, 0, 0, 0};

    for (int c0 = base; c0 < end; c0 += 64) {
        const int rem = min(64, end - c0);
        const int s_l = (lane < rem) ? csrc[c0 + lane] : 0;

        // weight table for this chunk: wlds[wv][j*8+h]
        const int nwc = (rem + 7) >> 3;
        for (int jj = 0; jj < nwc; ++jj) {
            const int j = jj * 8 + (lane >> 3);
            const int sj = __shfl(s_l, j);
            float w = 0.f;
            if (j < rem) w = __expf(lrelu(aS[(size_t)sj * 8 + hw] + adh));
            wlds[wv][j * 8 + hw] = w;
        }

        // gather: 4 edges per iteration, prefetch next 4 rows
        const int niter = (rem + 3) >> 2;
        int j = g;
        int scur = __shfl(s_l, j);
        uint4 pcur = zero4;
        if (j < rem) pcur = *(const uint4*)(Hm + (size_t)scur * 128 + i * 8);
        for (int tt = 0; tt < niter; ++tt) {
            const int jn = j + 4;
            const int snxt = __shfl(s_l, jn & 63);
            uint4 pnxt = zero4;
            if (jn < rem) pnxt = *(const uint4*)(Hm + (size_t)snxt * 128 + i * 8);
            float w = 0.f;
            if (j < rem) w = wlds[wv][j * 8 + hc];
            fma8(acc, pcur, w, ws);
            pcur = pnxt;
            j = jn;
        }
    }

    #pragma unroll
    for (int k = 0; k < 8; ++k) {
        acc[k] += __shfl_xor(acc[k], 16);
        acc[k] += __shfl_xor(acc[k], 32);
    }
    ws += __shfl_xor(ws, 16);
    ws += __shfl_xor(ws, 32);

    const float inv = 1.f / (ws + EPS);
    float v[8];
    #pragma unroll
    for (int k = 0; k < 8; ++k) v[k] = fmaxf(acc[k] * inv + bias[i * 8 + k], 0.f);

    // fused layer-2 attention dots: a2 = v . (W2 @ att2)
    float ps = 0.f, pd = 0.f;
    #pragma unroll
    for (int k = 0; k < 8; ++k) { ps += v[k] * vs[i * 8 + k]; pd += v[k] * vd[i * 8 + k]; }
    #pragma unroll
    for (int off = 1; off <= 8; off <<= 1) {
        ps += __shfl_xor(ps, off);
        pd += __shfl_xor(pd, off);
    }
    if (lane == 0) { aS2[d] = ps; aD2[d] = pd; }

    if (g == 0) {
        uint4 pk;
        pk.x = (uint)f2bf(v[0]) | ((uint)f2bf(v[1]) << 16);
        pk.y = (uint)f2bf(v[2]) | ((uint)f2bf(v[3]) << 16);
        pk.z = (uint)f2bf(v[4]) | ((uint)f2bf(v[5]) << 16);
        pk.w = (uint)f2bf(v[6]) | ((uint)f2bf(v[7]) << 16);
        *(uint4*)(o1bf + (size_t)d * 128 + i * 8) = pk;
    }
}

// ---------------- agg layer 2: single head ----------------
__global__ __launch_bounds__(256) void agg1(const int* __restrict__ rowptr,
                                            const int* __restrict__ csrc,
                                            const float* __restrict__ aS,
                                            const float* __restrict__ aD,
                                            const ushort* __restrict__ Hm,
                                            const float* __restrict__ bias,
                                            float* __restrict__ out) {
    const int wv = threadIdx.x >> 6;
    const int d = blockIdx.x * 4 + wv;
    const int lane = threadIdx.x & 63;
    const int g = lane >> 4, i = lane & 15;
    const float ad = aD[d];

    const int base = rowptr[d], end = rowptr[d + 1];
    float acc[8] = {0.f, 0.f, 0.f, 0.f, 0.f, 0.f, 0.f, 0.f};
    float ws = 0.f;
    const uint4 zero4 = {0, 0, 0, 0};

    for (int c0 = base; c0 < end; c0 += 64) {
        const int rem = min(64, end - c0);
        const int s_l = (lane < rem) ? csrc[c0 + lane] : 0;
        const float w_l = (lane < rem) ? __expf(lrelu(aS[s_l] + ad)) : 0.f;

        const int niter = (rem + 3) >> 2;
        int j = g;
        int scur = __shfl(s_l, j);
        float wcur = __shfl(w_l, j);
        uint4 pcur = zero4;
        if (j < rem) pcur = *(const uint4*)(Hm + (size_t)scur * 128 + i * 8);
        for (int tt = 0; tt < niter; ++tt) {
            const int jn = j + 4;
            const int snxt = __shfl(s_l, jn & 63);
            const float wnxt = __shfl(w_l, jn & 63);
            uint4 pnxt = zero4;
            if (jn < rem) pnxt = *(const uint4*)(Hm + (size_t)snxt * 128 + i * 8);
            fma8(acc, pcur, wcur, ws);
            pcur = pnxt;
            wcur = wnxt;
            j = jn;
        }
    }

    #pragma unroll
    for (int k = 0; k < 8; ++k) {
        acc[k] += __shfl_xor(acc[k], 16);
        acc[k] += __shfl_xor(acc[k], 32);
    }
    ws += __shfl_xor(ws, 16);
    ws += __shfl_xor(ws, 32);

    if (g == 0) {
        const float inv = 1.f / (ws + EPS);
        float4 o0, o1v;
        o0.x = acc[0] * inv + bias[i * 8 + 0];
        o0.y = acc[1] * inv + bias[i * 8 + 1];
        o0.z = acc[2] * inv + bias[i * 8 + 2];
        o0.w = acc[3] * inv + bias[i * 8 + 3];
        o1v.x = acc[4] * inv + bias[i * 8 + 4];
        o1v.y = acc[5] * inv + bias[i * 8 + 5];
        o1v.z = acc[6] * inv + bias[i * 8 + 6];
        o1v.w = acc[7] * inv + bias[i * 8 + 7];
        *(float4*)(out + (size_t)d * 128 + i * 8) = o0;
        *(float4*)(out + (size_t)d * 128 + i * 8 + 4) = o1v;
    }
}

extern "C" void kernel_launch(void* const* d_in, const int* in_sizes, int n_in,
                              void* d_out, int out_size, void* d_ws, size_t ws_size,
                              hipStream_t stream) {
    const float* x        = (const float*)d_in[0];
    const int*   ei       = (const int*)  d_in[1];
    const float* W1       = (const float*)d_in[2];
    const float* att_src1 = (const float*)d_in[3];
    const float* att_dst1 = (const float*)d_in[4];
    const float* b1       = (const float*)d_in[5];
    const float* W2       = (const float*)d_in[6];
    const float* att_src2 = (const float*)d_in[7];
    const float* att_dst2 = (const float*)d_in[8];
    const float* b2       = (const float*)d_in[9];
    float* out = (float*)d_out;

    // Workspace layout
    ushort* Hbf  = (ushort*)d_ws;                          // N*128 bf16 (h1, then h2)
    ushort* o1bf = Hbf + (size_t)N_NODES * 128;            // N*128 bf16
    float*  aS1  = (float*)(o1bf + (size_t)N_NODES * 128); // N*8
    float*  aD1  = aS1 + (size_t)N_NODES * 8;              // N*8
    float*  aS2  = aD1 + (size_t)N_NODES * 8;              // N
    float*  aD2  = aS2 + N_NODES;                          // N
    float*  vs   = aD2 + N_NODES;                          // 128
    float*  vd   = vs + 128;                               // 128
    ushort* W1t  = (ushort*)(vd + 128);                    // 128*128
    ushort* W2t  = W1t + 128 * 128;                        // 128*128
    uint* cnt16  = (uint*)(W2t + 128 * 128);               // (N+1)/2 words
    int* rowptr  = (int*)(cnt16 + (N_NODES + 1) / 2 + 1);  // N+1
    int* bsum    = rowptr + N_NODES + 1;                   // 128
    ushort* rank = (ushort*)(bsum + 128);                  // ETOT
    int* csrc    = (int*)(rank + ETOT + 2);                // ETOT

    const int zblk = ((N_NODES + 1) / 2 + 255) / 256;
    const int eblk = (ETOT + 255) / 256;
    const int gemm_blocks = (N_NODES + 63) / 64;           // 782
    const int agg_blocks = N_NODES / 4;                    // 12500

    convert_W<<<2, 256, 0, stream>>>(W1, W2, att_src2, att_dst2, W1t, W2t, vs, vd);
    zero_counts<<<zblk, 256, 0, stream>>>(cnt16);
    count_rank<<<eblk, 256, 0, stream>>>(ei, cnt16, rank);
    block_sums<<<NBLK_SCAN, SCAN_BLK, 0, stream>>>(cnt16, bsum);
    scan98<<<1, 128, 0, stream>>>(bsum);
    scan_final<<<NBLK_SCAN, SCAN_BLK, 0, stream>>>(cnt16, bsum, rowptr);
    scatter_kernel<<<eblk, 256, 0, stream>>>(ei, rowptr, rank, csrc);

    // Layer 1
    mfma_gemm<false, true><<<gemm_blocks, 256, 0, stream>>>(
        x, W1t, Hbf, att_src1, att_dst1, aS1, aD1, N_NODES);
    agg8<<<agg_blocks, 256, 0, stream>>>(
        rowptr, csrc, aS1, aD1, Hbf, b1, vs, vd, o1bf, aS2, aD2);

    // Layer 2
    mfma_gemm<true, false><<<gemm_blocks, 256, 0, stream>>>(
        o1bf, W2t, Hbf, nullptr, nullptr, nullptr, nullptr, N_NODES);
    agg1<<<agg_blocks, 256, 0, stream>>>(
        rowptr, csrc, aS2, aD2, Hbf, b2, out);
}